// Round 6
// baseline (30598.315 us; speedup 1.0000x reference)
//
#include <hip/hip_runtime.h>
#include <hip/hip_bf16.h>

__device__ __forceinline__ float wsum64(float v) {
#pragma unroll
  for (int m = 32; m > 0; m >>= 1) v += __shfl_xor(v, m, 64);
  return v;
}
__device__ __forceinline__ float gsum16(float v) {
#pragma unroll
  for (int m = 8; m > 0; m >>= 1) v += __shfl_xor(v, m, 16);
  return v;
}
__device__ __forceinline__ float lrelu(float x) { return x > 0.f ? x : 0.2f * x; }
__device__ __forceinline__ float sigf(float x) { return 1.f / (1.f + __expf(-x)); }
__device__ __forceinline__ float dp4(float4 a, float4 b) {
  return a.x * b.x + a.y * b.y + a.z * b.z + a.w * b.w;
}

#define MM1(f, row)                                        \
  {                                                        \
    float4 w_ = W4[(row) * 16 + l16];                      \
    acc.x = fmaf((f), w_.x, acc.x);                        \
    acc.y = fmaf((f), w_.y, acc.y);                        \
    acc.z = fmaf((f), w_.z, acc.z);                        \
    acc.w = fmaf((f), w_.w, acc.w);                        \
  }

#define MM2(f, row)                                        \
  {                                                        \
    float4 wr_ = W4[(row) * 32 + l16];                     \
    float4 wz_ = W4[(row) * 32 + 16 + l16];                \
    aR.x = fmaf((f), wr_.x, aR.x);                         \
    aR.y = fmaf((f), wr_.y, aR.y);                         \
    aR.z = fmaf((f), wr_.z, aR.z);                         \
    aR.w = fmaf((f), wr_.w, aR.w);                         \
    aZ.x = fmaf((f), wz_.x, aZ.x);                         \
    aZ.y = fmaf((f), wz_.y, aZ.y);                         \
    aZ.z = fmaf((f), wz_.z, aZ.z);                         \
    aZ.w = fmaf((f), wz_.w, aZ.w);                         \
  }

// ---------------- CSR build ----------------
__global__ void hist_k(const int* __restrict__ dst, int* __restrict__ cnt, int e) {
  int i = blockIdx.x * blockDim.x + threadIdx.x;
  if (i < e) atomicAdd(&cnt[dst[i]], 1);
}

__global__ __launch_bounds__(256) void bsum_k(const int* __restrict__ cnt,
                                              int* __restrict__ bsum, int n) {
  __shared__ int red[4];
  int base = blockIdx.x * 1024;
  int t = threadIdx.x;
  int v = 0;
#pragma unroll
  for (int i = 0; i < 4; i++) {
    int idx = base + t + i * 256;
    v += (idx < n) ? cnt[idx] : 0;
  }
#pragma unroll
  for (int m = 32; m > 0; m >>= 1) v += __shfl_xor(v, m, 64);
  if ((t & 63) == 0) red[t >> 6] = v;
  __syncthreads();
  if (t == 0) bsum[blockIdx.x] = red[0] + red[1] + red[2] + red[3];
}

__global__ __launch_bounds__(1024) void scan_bsum_k(int* __restrict__ bsum,
                                                    int* __restrict__ rpn, int nb) {
  __shared__ int buf[1024];
  int t = threadIdx.x;
  int v = (t < nb) ? bsum[t] : 0;
  buf[t] = v;
  __syncthreads();
  int val = v;
  for (int off = 1; off < 1024; off <<= 1) {
    int u = (t >= off) ? buf[t - off] : 0;
    __syncthreads();
    val += u;
    buf[t] = val;
    __syncthreads();
  }
  if (t < nb) bsum[t] = val - v;
  if (t == nb - 1) *rpn = val;
}

__global__ __launch_bounds__(1024) void scan_fin_k(const int* __restrict__ cnt,
                                                   const int* __restrict__ bsum,
                                                   int* __restrict__ rp,
                                                   int* __restrict__ cursor, int n) {
  __shared__ int buf[1024];
  int t = threadIdx.x;
  int idx = blockIdx.x * 1024 + t;
  int v = (idx < n) ? cnt[idx] : 0;
  buf[t] = v;
  __syncthreads();
  int val = v;
  for (int off = 1; off < 1024; off <<= 1) {
    int u = (t >= off) ? buf[t - off] : 0;
    __syncthreads();
    val += u;
    buf[t] = val;
    __syncthreads();
  }
  if (idx < n) {
    int e = bsum[blockIdx.x] + val - v;
    rp[idx] = e;
    cursor[idx] = e;
  }
}

__global__ void scatter_k(const int* __restrict__ src, const int* __restrict__ dst,
                          int* __restrict__ cursor, int* __restrict__ srcs, int e) {
  int i = blockIdx.x * blockDim.x + threadIdx.x;
  if (i < e) {
    int pos = atomicAdd(&cursor[dst[i]], 1);
    srcs[pos] = src[i];
  }
}

// ---------------- standalone mm for the very first r,z gates ----------------
template <int FA>
__global__ __launch_bounds__(512) void mm0_k(
    const float* __restrict__ xa, const float* __restrict__ xb,
    const float* __restrict__ Wg, const float* __restrict__ al, const float* __restrict__ ar,
    float* __restrict__ hb, float* __restrict__ el, float* __restrict__ er, int n) {
  constexpr int KP = FA + 64;
  __shared__ float Wl[KP * 128];
  __shared__ float Xl[32 * KP];
  for (int i = threadIdx.x; i < KP * 64; i += 512) {
    float2 wv = {Wg[i], Wg[(size_t)KP * 64 + i]};
    *(float2*)&Wl[i * 2] = wv;
  }
  int rbase = blockIdx.x * 32;
  for (int i = threadIdx.x; i < 32 * KP; i += 512) {
    int row = i / KP, k = i - row * KP;
    int r = rbase + row; if (r >= n) r = n - 1;
    Xl[i] = (k < FA) ? xa[(size_t)r * FA + k] : xb[(size_t)r * 64 + (k - FA)];
  }
  __syncthreads();
  int lane = threadIdx.x & 63, w = threadIdx.x >> 6;
  int rb = rbase + w * 4;
  if (rb >= n) return;
  float alr = al[lane], arr_ = ar[lane];
  float alz = al[64 + lane], arz = ar[64 + lane];
  float accr[4], accz[4];
#pragma unroll
  for (int i = 0; i < 4; i++) { accr[i] = 0.f; accz[i] = 0.f; }
  const int xoff = (w * 4) * KP;
#pragma unroll 8
  for (int k = 0; k < KP; k += 2) {
    float2 w0 = *(const float2*)&Wl[(k * 64 + lane) * 2];
    float2 w1 = *(const float2*)&Wl[((k + 1) * 64 + lane) * 2];
#pragma unroll
    for (int i = 0; i < 4; i++) {
      float2 xv = *(const float2*)&Xl[xoff + i * KP + k];
      accr[i] = fmaf(xv.x, w0.x, accr[i]);
      accz[i] = fmaf(xv.x, w0.y, accz[i]);
      accr[i] = fmaf(xv.y, w1.x, accr[i]);
      accz[i] = fmaf(xv.y, w1.y, accz[i]);
    }
  }
#pragma unroll
  for (int i = 0; i < 4; i++) {
    int r = rb + i;
    bool ok = r < n;
    if (ok) {
      hb[(size_t)r * 128 + lane] = accr[i];
      hb[(size_t)r * 128 + 64 + lane] = accz[i];
    }
    float s0 = wsum64(accr[i] * alr);
    float s1 = wsum64(accz[i] * alz);
    float s2 = wsum64(accr[i] * arr_);
    float s3 = wsum64(accz[i] * arz);
    if (ok && lane == 0) {
      el[(size_t)r * 2 + 0] = s0;
      el[(size_t)r * 2 + 1] = s1;
      er[(size_t)r * 2 + 0] = s2;
      er[(size_t)r * 2 + 1] = s3;
    }
  }
}

// ---------------- K_B: agg r,z + fused candidate mm ----------------
// feat_c = [r*hx | xa] with W_c rows permuted to match.
template <int FA>
__global__ __launch_bounds__(512) void kb_k(
    const int* __restrict__ rp, const int* __restrict__ srcs,
    const float* __restrict__ hbuf, const float* __restrict__ elrz,
    const float* __restrict__ errz, const float* __restrict__ b,
    const float* __restrict__ xa, const float* __restrict__ hx,
    const float* __restrict__ Wc, const float* __restrict__ alc,
    const float* __restrict__ arc,
    float* __restrict__ hc, float* __restrict__ elc, float* __restrict__ erc,
    float* __restrict__ zb, int n) {
  constexpr int KP = FA + 64;
  __shared__ float WlC[KP * 64];
  for (int i = threadIdx.x; i < KP * 64; i += 512) {
    int k = i >> 6, c = i & 63;
    int ks = (k < 64) ? (FA + k) : (k - 64);   // [hx-part | xa-part] row order
    WlC[i] = Wc[(size_t)ks * 64 + c];
  }
  __syncthreads();
  int l16 = threadIdx.x & 15;
  int d = blockIdx.x * 32 + (threadIdx.x >> 4);
  if (d >= n) return;
  int beg = rp[d], deg = rp[d + 1] - beg;
  float2 erd = ((const float2*)errz)[d];
  const float4* h4 = (const float4*)hbuf;
  float4 accr = {0, 0, 0, 0}, accz = {0, 0, 0, 0};
  float sr = 0.f, sz = 0.f;
  for (int base = 0; base < deg; base += 16) {
    int k = base + l16;
    int s = 0;
    float exr = 0.f, exz = 0.f;
    if (k < deg) {
      s = srcs[beg + k];
      float2 el = ((const float2*)elrz)[s];
      exr = __expf(lrelu(el.x + erd.x));
      exz = __expf(lrelu(el.y + erd.y));
      sr += exr; sz += exz;
    }
#pragma unroll
    for (int j = 0; j < 16; j++) {
      int sj = __shfl(s, j, 16);
      float aj = __shfl(exr, j, 16);
      float zj = __shfl(exz, j, 16);
      float4 hr = h4[(size_t)sj * 32 + l16];
      float4 hz = h4[(size_t)sj * 32 + 16 + l16];
      accr.x = fmaf(aj, hr.x, accr.x); accr.y = fmaf(aj, hr.y, accr.y);
      accr.z = fmaf(aj, hr.z, accr.z); accr.w = fmaf(aj, hr.w, accr.w);
      accz.x = fmaf(zj, hz.x, accz.x); accz.y = fmaf(zj, hz.y, accz.y);
      accz.z = fmaf(zj, hz.z, accz.z); accz.w = fmaf(zj, hz.w, accz.w);
    }
  }
  sr = gsum16(sr); sz = gsum16(sz);
  float invr = 1.f / fmaxf(sr, 1e-9f);
  float invz = 1.f / fmaxf(sz, 1e-9f);
  float4 br4 = ((const float4*)b)[l16];
  float4 bz4 = ((const float4*)(b + 64))[l16];
  float4 hx4 = ((const float4*)hx)[(size_t)d * 16 + l16];
  float4 rv, zv;
  rv.x = sigf(fmaf(accr.x, invr, br4.x)) * hx4.x;
  rv.y = sigf(fmaf(accr.y, invr, br4.y)) * hx4.y;
  rv.z = sigf(fmaf(accr.z, invr, br4.z)) * hx4.z;
  rv.w = sigf(fmaf(accr.w, invr, br4.w)) * hx4.w;
  zv.x = sigf(fmaf(accz.x, invz, bz4.x));
  zv.y = sigf(fmaf(accz.y, invz, bz4.y));
  zv.z = sigf(fmaf(accz.z, invz, bz4.z));
  zv.w = sigf(fmaf(accz.w, invz, bz4.w));
  ((float4*)zb)[(size_t)d * 16 + l16] = zv;
  // fused mm_c
  const float4* W4 = (const float4*)WlC;
  float4 acc = {0, 0, 0, 0};
#pragma unroll
  for (int o = 0; o < 16; o++) {
    float f0 = __shfl(rv.x, o, 16);
    float f1 = __shfl(rv.y, o, 16);
    float f2 = __shfl(rv.z, o, 16);
    float f3 = __shfl(rv.w, o, 16);
    MM1(f0, 4 * o + 0); MM1(f1, 4 * o + 1);
    MM1(f2, 4 * o + 2); MM1(f3, 4 * o + 3);
  }
  if (FA == 2) {
    float f0 = xa[(size_t)d * 2 + 0];
    float f1 = xa[(size_t)d * 2 + 1];
    MM1(f0, 64); MM1(f1, 65);
  } else {
    float4 xv = ((const float4*)xa)[(size_t)d * 16 + l16];
#pragma unroll
    for (int o = 0; o < 16; o++) {
      float f0 = __shfl(xv.x, o, 16);
      float f1 = __shfl(xv.y, o, 16);
      float f2 = __shfl(xv.z, o, 16);
      float f3 = __shfl(xv.w, o, 16);
      MM1(f0, 64 + 4 * o + 0); MM1(f1, 64 + 4 * o + 1);
      MM1(f2, 64 + 4 * o + 2); MM1(f3, 64 + 4 * o + 3);
    }
  }
  float4 alv = ((const float4*)alc)[l16];
  float4 arv = ((const float4*)arc)[l16];
  float sl = gsum16(dp4(acc, alv));
  float sr2 = gsum16(dp4(acc, arv));
  if (l16 == 0) { elc[d] = sl; erc[d] = sr2; }
  ((float4*)hc)[(size_t)d * 16 + l16] = acc;
}

// ---------------- K_C: agg candidate + state update (+proj) + fused next mm_rz ----------------
template <int FAN, bool NEXT>
__global__ __launch_bounds__(512) void kc_k(
    const int* __restrict__ rp, const int* __restrict__ srcs,
    const float* __restrict__ hc, const float* __restrict__ elc,
    const float* __restrict__ erc, const float* __restrict__ bc,
    const float* __restrict__ zb, float* __restrict__ hstate,
    const float* __restrict__ projW, const float* __restrict__ projb,
    float* __restrict__ outp,
    const float* __restrict__ Wn, const float* __restrict__ aln,
    const float* __restrict__ arn, const float* __restrict__ xan,
    const float* __restrict__ hxn,
    float* __restrict__ hbn, float* __restrict__ elrzn, float* __restrict__ errzn,
    int n) {
  constexpr int KPN = FAN + 64;
  __shared__ float WlN[NEXT ? KPN * 128 : 1];
  if constexpr (NEXT) {
    for (int i = threadIdx.x; i < KPN * 128; i += 512) {
      int k = i >> 7, gc = i & 127;
      int g = gc >> 6, c = gc & 63;
      int ks = (k < 64) ? (FAN + k) : (k - 64);   // [hx | xa] row order
      WlN[i] = Wn[((size_t)g * KPN + ks) * 64 + c];
    }
    __syncthreads();
  }
  int l16 = threadIdx.x & 15;
  int d = blockIdx.x * 32 + (threadIdx.x >> 4);
  if (d >= n) return;
  int beg = rp[d], deg = rp[d + 1] - beg;
  float erd = erc[d];
  const float4* h4 = (const float4*)hc;
  float4 acc = {0, 0, 0, 0};
  float ssum = 0.f;
  for (int base = 0; base < deg; base += 16) {
    int k = base + l16;
    int s = 0;
    float ex = 0.f;
    if (k < deg) {
      s = srcs[beg + k];
      ex = __expf(lrelu(elc[s] + erd));
      ssum += ex;
    }
#pragma unroll
    for (int j = 0; j < 16; j++) {
      int sj = __shfl(s, j, 16);
      float aj = __shfl(ex, j, 16);
      float4 hv = h4[(size_t)sj * 16 + l16];
      acc.x = fmaf(aj, hv.x, acc.x); acc.y = fmaf(aj, hv.y, acc.y);
      acc.z = fmaf(aj, hv.z, acc.z); acc.w = fmaf(aj, hv.w, acc.w);
    }
  }
  ssum = gsum16(ssum);
  float inv = 1.f / fmaxf(ssum, 1e-9f);
  float4 bc4 = ((const float4*)bc)[l16];
  float4 z4 = ((const float4*)zb)[(size_t)d * 16 + l16];
  float4 hx4 = ((const float4*)hstate)[(size_t)d * 16 + l16];
  float4 hcv, hn;
  hcv.x = tanhf(fmaf(acc.x, inv, bc4.x));
  hcv.y = tanhf(fmaf(acc.y, inv, bc4.y));
  hcv.z = tanhf(fmaf(acc.z, inv, bc4.z));
  hcv.w = tanhf(fmaf(acc.w, inv, bc4.w));
  hn.x = z4.x * hx4.x + (1.f - z4.x) * hcv.x;
  hn.y = z4.y * hx4.y + (1.f - z4.y) * hcv.y;
  hn.z = z4.z * hx4.z + (1.f - z4.z) * hcv.z;
  hn.w = z4.w * hx4.w + (1.f - z4.w) * hcv.w;
  ((float4*)hstate)[(size_t)d * 16 + l16] = hn;
  float p0 = 0.f, p1 = 0.f;
  if (outp) {
    const float4* wp4 = (const float4*)projW;   // [64][2] row-major
    float4 a0 = wp4[l16 * 2], a1 = wp4[l16 * 2 + 1];
    p0 = gsum16(hn.x * a0.x + hn.y * a0.z + hn.z * a1.x + hn.w * a1.z) + projb[0];
    p1 = gsum16(hn.x * a0.y + hn.y * a0.w + hn.z * a1.y + hn.w * a1.w) + projb[1];
    if (l16 == 0) {
      outp[(size_t)d * 2 + 0] = p0;
      outp[(size_t)d * 2 + 1] = p1;
    }
  }
  if constexpr (NEXT) {
    const float4* W4 = (const float4*)WlN;
    float4 hxn4 = ((const float4*)hxn)[(size_t)d * 16 + l16];
    float4 aR = {0, 0, 0, 0}, aZ = {0, 0, 0, 0};
#pragma unroll
    for (int o = 0; o < 16; o++) {
      float f0 = __shfl(hxn4.x, o, 16);
      float f1 = __shfl(hxn4.y, o, 16);
      float f2 = __shfl(hxn4.z, o, 16);
      float f3 = __shfl(hxn4.w, o, 16);
      MM2(f0, 4 * o + 0); MM2(f1, 4 * o + 1);
      MM2(f2, 4 * o + 2); MM2(f3, 4 * o + 3);
    }
    if (FAN == 2) {
      float f0, f1;
      if (xan) { f0 = xan[(size_t)d * 2 + 0]; f1 = xan[(size_t)d * 2 + 1]; }
      else { f0 = p0; f1 = p1; }   // decoder pred chain (computed above)
      MM2(f0, 64); MM2(f1, 65);
    } else {
      float4 xv = xan ? ((const float4*)xan)[(size_t)d * 16 + l16] : hn;
#pragma unroll
      for (int o = 0; o < 16; o++) {
        float f0 = __shfl(xv.x, o, 16);
        float f1 = __shfl(xv.y, o, 16);
        float f2 = __shfl(xv.z, o, 16);
        float f3 = __shfl(xv.w, o, 16);
        MM2(f0, 64 + 4 * o + 0); MM2(f1, 64 + 4 * o + 1);
        MM2(f2, 64 + 4 * o + 2); MM2(f3, 64 + 4 * o + 3);
      }
    }
    float4 alr4 = ((const float4*)aln)[l16];
    float4 alz4 = ((const float4*)(aln + 64))[l16];
    float4 arr4 = ((const float4*)arn)[l16];
    float4 arz4 = ((const float4*)(arn + 64))[l16];
    float e0 = gsum16(dp4(aR, alr4));
    float e1 = gsum16(dp4(aZ, alz4));
    float e2 = gsum16(dp4(aR, arr4));
    float e3 = gsum16(dp4(aZ, arz4));
    if (l16 == 0) {
      elrzn[(size_t)d * 2 + 0] = e0;
      elrzn[(size_t)d * 2 + 1] = e1;
      errzn[(size_t)d * 2 + 0] = e2;
      errzn[(size_t)d * 2 + 1] = e3;
    }
    ((float4*)hbn)[(size_t)d * 32 + l16] = aR;
    ((float4*)hbn)[(size_t)d * 32 + 16 + l16] = aZ;
  }
}

extern "C" void kernel_launch(void* const* d_in, const int* in_sizes, int n_in,
                              void* d_out, int out_size, void* d_ws, size_t ws_size,
                              hipStream_t stream) {
  const int T = 12, F = 2, H = 64;
  const float* x = (const float*)d_in[0];
  const int* src = (const int*)d_in[1];
  const int* dst = (const int*)d_in[2];
  const float* Ws[4] = {(const float*)d_in[3], (const float*)d_in[7],
                        (const float*)d_in[11], (const float*)d_in[15]};
  const float* als[4] = {(const float*)d_in[4], (const float*)d_in[8],
                         (const float*)d_in[12], (const float*)d_in[16]};
  const float* ars[4] = {(const float*)d_in[5], (const float*)d_in[9],
                         (const float*)d_in[13], (const float*)d_in[17]};
  const float* bs[4] = {(const float*)d_in[6], (const float*)d_in[10],
                        (const float*)d_in[14], (const float*)d_in[18]};
  const float* proj_W = (const float*)d_in[19];
  const float* proj_b = (const float*)d_in[20];
  float* out = (float*)d_out;

  const int E = in_sizes[1];
  const int N = in_sizes[0] / (T * F);
  const int NB = (N + 1023) / 1024;

  char* wp = (char*)d_ws;
  size_t off = 0;
  auto carve = [&](size_t bytes) {
    void* p = wp + off;
    off = (off + bytes + 255) & ~(size_t)255;
    return p;
  };
  int* counts = (int*)carve((size_t)N * 4);
  int* bsum = (int*)carve((size_t)NB * 4);
  int* rp = (int*)carve((size_t)(N + 1) * 4);
  int* cursor = (int*)carve((size_t)N * 4);
  int* srcs = (int*)carve((size_t)E * 4);
  float* hs0 = (float*)carve((size_t)N * H * 4);
  float* hs1 = (float*)carve((size_t)N * H * 4);
  float* hbuf = (float*)carve((size_t)N * 2 * H * 4);
  float* elrz = (float*)carve((size_t)N * 2 * 4);
  float* errz = (float*)carve((size_t)N * 2 * 4);
  float* hcb = (float*)carve((size_t)N * H * 4);
  float* elc = (float*)carve((size_t)N * 4);
  float* erc = (float*)carve((size_t)N * 4);
  float* zbuf = (float*)carve((size_t)N * H * 4);
  float* zero2 = (float*)carve((size_t)N * F * 4);
  (void)ws_size;

  const int G_E = (E + 255) / 256;
  const int G32 = (N + 31) / 32;

  // ---- CSR by destination ----
  hipMemsetAsync(counts, 0, (size_t)N * 4, stream);
  hist_k<<<G_E, 256, 0, stream>>>(dst, counts, E);
  bsum_k<<<NB, 256, 0, stream>>>(counts, bsum, N);
  scan_bsum_k<<<1, 1024, 0, stream>>>(bsum, rp + N, NB);
  scan_fin_k<<<NB, 1024, 0, stream>>>(counts, bsum, rp, cursor, N);
  scatter_k<<<G_E, 256, 0, stream>>>(src, dst, cursor, srcs, E);

  // ---- init states ----
  hipMemsetAsync(hs0, 0, (size_t)N * H * 4, stream);
  hipMemsetAsync(hs1, 0, (size_t)N * H * 4, stream);
  hipMemsetAsync(zero2, 0, (size_t)N * F * 4, stream);

  // ---- initial r,z dense for enc layer0 t=0 ----
  mm0_k<2><<<G32, 512, 0, stream>>>(x, hs0, Ws[0], als[0], ars[0], hbuf, elrz, errz, N);

  // ---- 48 GRU cells, 2 kernels each ----
  for (int i = 0; i < 48; i++) {
    bool enc = i < 24;
    int j = enc ? i : i - 24;
    int t = j >> 1, layer = j & 1;
    int type = (enc ? 0 : 2) + layer;
    const float* W = Ws[type];
    const float* al = als[type];
    const float* ar = ars[type];
    const float* b = bs[type];
    int FA = layer ? 64 : 2;
    size_t KP = FA + 64;
    const float* Wc = W + (size_t)2 * KP * 64;
    const float* xa = layer ? hs0
                            : (enc ? x + (size_t)t * N * 2
                                   : (t == 0 ? zero2 : out + (size_t)(t - 1) * N * 2));
    float* hstate = layer ? hs1 : hs0;
    float* outp = (!enc && layer) ? out + (size_t)t * N * 2 : nullptr;

    if (FA == 2)
      kb_k<2><<<G32, 512, 0, stream>>>(rp, srcs, hbuf, elrz, errz, b, xa, hstate,
                                       Wc, al + 128, ar + 128, hcb, elc, erc, zbuf, N);
    else
      kb_k<64><<<G32, 512, 0, stream>>>(rp, srcs, hbuf, elrz, errz, b, xa, hstate,
                                        Wc, al + 128, ar + 128, hcb, elc, erc, zbuf, N);

    if (i == 47) {
      kc_k<2, false><<<G32, 512, 0, stream>>>(
          rp, srcs, hcb, elc, erc, b + 128, zbuf, hstate, proj_W, proj_b, outp,
          nullptr, nullptr, nullptr, nullptr, nullptr, nullptr, nullptr, nullptr, N);
    } else {
      int i2 = i + 1;
      bool enc2 = i2 < 24;
      int j2 = enc2 ? i2 : i2 - 24;
      int t2 = j2 >> 1, l2 = j2 & 1;
      int type2 = (enc2 ? 0 : 2) + l2;
      const float* Wn = Ws[type2];
      const float* aln = als[type2];
      const float* arn = ars[type2];
      const float* xan = nullptr;   // local hn / local pred by default
      if (l2 == 0) {
        if (enc2) xan = x + (size_t)t2 * N * 2;     // next enc layer0
        else if (t2 == 0) xan = zero2;              // first decoder step
        // else: decoder pred chain -> local p0,p1
      }
      float* hxn = l2 ? hs1 : hs0;
      if (l2)
        kc_k<64, true><<<G32, 512, 0, stream>>>(
            rp, srcs, hcb, elc, erc, b + 128, zbuf, hstate, proj_W, proj_b, outp,
            Wn, aln, arn, xan, hxn, hbuf, elrz, errz, N);
      else
        kc_k<2, true><<<G32, 512, 0, stream>>>(
            rp, srcs, hcb, elc, erc, b + 128, zbuf, hstate, proj_W, proj_b, outp,
            Wn, aln, arn, xan, hxn, hbuf, elrz, errz, N);
    }
  }
  (void)out_size; (void)n_in;
}

// Round 7
// 8056.178 us; speedup vs baseline: 3.7981x; 3.7981x over previous
//
#include <hip/hip_runtime.h>
#include <hip/hip_bf16.h>

__device__ __forceinline__ float wsum64(float v) {
#pragma unroll
  for (int m = 32; m > 0; m >>= 1) v += __shfl_xor(v, m, 64);
  return v;
}
__device__ __forceinline__ float gsum16(float v) {
#pragma unroll
  for (int m = 8; m > 0; m >>= 1) v += __shfl_xor(v, m, 16);
  return v;
}
__device__ __forceinline__ float lrelu(float x) { return x > 0.f ? x : 0.2f * x; }
__device__ __forceinline__ float sigf(float x) { return 1.f / (1.f + __expf(-x)); }
__device__ __forceinline__ float dp4(float4 a, float4 b) {
  return a.x * b.x + a.y * b.y + a.z * b.z + a.w * b.w;
}

#define MM1(f, row)                                        \
  {                                                        \
    float4 w_ = W4[(row) * 16 + l16];                      \
    acc.x = fmaf((f), w_.x, acc.x);                        \
    acc.y = fmaf((f), w_.y, acc.y);                        \
    acc.z = fmaf((f), w_.z, acc.z);                        \
    acc.w = fmaf((f), w_.w, acc.w);                        \
  }

// ---------------- CSR build ----------------
__global__ void hist_k(const int* __restrict__ dst, int* __restrict__ cnt, int e) {
  int i = blockIdx.x * blockDim.x + threadIdx.x;
  if (i < e) atomicAdd(&cnt[dst[i]], 1);
}

__global__ __launch_bounds__(256) void bsum_k(const int* __restrict__ cnt,
                                              int* __restrict__ bsum, int n) {
  __shared__ int red[4];
  int base = blockIdx.x * 1024;
  int t = threadIdx.x;
  int v = 0;
#pragma unroll
  for (int i = 0; i < 4; i++) {
    int idx = base + t + i * 256;
    v += (idx < n) ? cnt[idx] : 0;
  }
#pragma unroll
  for (int m = 32; m > 0; m >>= 1) v += __shfl_xor(v, m, 64);
  if ((t & 63) == 0) red[t >> 6] = v;
  __syncthreads();
  if (t == 0) bsum[blockIdx.x] = red[0] + red[1] + red[2] + red[3];
}

__global__ __launch_bounds__(1024) void scan_bsum_k(int* __restrict__ bsum,
                                                    int* __restrict__ rpn, int nb) {
  __shared__ int buf[1024];
  int t = threadIdx.x;
  int v = (t < nb) ? bsum[t] : 0;
  buf[t] = v;
  __syncthreads();
  int val = v;
  for (int off = 1; off < 1024; off <<= 1) {
    int u = (t >= off) ? buf[t - off] : 0;
    __syncthreads();
    val += u;
    buf[t] = val;
    __syncthreads();
  }
  if (t < nb) bsum[t] = val - v;
  if (t == nb - 1) *rpn = val;
}

__global__ __launch_bounds__(1024) void scan_fin_k(const int* __restrict__ cnt,
                                                   const int* __restrict__ bsum,
                                                   int* __restrict__ rp,
                                                   int* __restrict__ cursor, int n) {
  __shared__ int buf[1024];
  int t = threadIdx.x;
  int idx = blockIdx.x * 1024 + t;
  int v = (idx < n) ? cnt[idx] : 0;
  buf[t] = v;
  __syncthreads();
  int val = v;
  for (int off = 1; off < 1024; off <<= 1) {
    int u = (t >= off) ? buf[t - off] : 0;
    __syncthreads();
    val += u;
    buf[t] = val;
    __syncthreads();
  }
  if (idx < n) {
    int e = bsum[blockIdx.x] + val - v;
    rp[idx] = e;
    cursor[idx] = e;
  }
}

__global__ void scatter_k(const int* __restrict__ src, const int* __restrict__ dst,
                          int* __restrict__ cursor, int* __restrict__ srcs, int e) {
  int i = blockIdx.x * blockDim.x + threadIdx.x;
  if (i < e) {
    int pos = atomicAdd(&cursor[dst[i]], 1);
    srcs[pos] = src[i];
  }
}

// ---------------- standalone mm for the very first r,z gates ----------------
template <int FA>
__global__ __launch_bounds__(512) void mm0_k(
    const float* __restrict__ xa, const float* __restrict__ xb,
    const float* __restrict__ Wg, const float* __restrict__ al, const float* __restrict__ ar,
    float* __restrict__ hb, float* __restrict__ el, float* __restrict__ er, int n) {
  constexpr int KP = FA + 64;
  __shared__ float Wl[KP * 128];
  __shared__ float Xl[32 * KP];
  for (int i = threadIdx.x; i < KP * 64; i += 512) {
    float2 wv = {Wg[i], Wg[(size_t)KP * 64 + i]};
    *(float2*)&Wl[i * 2] = wv;
  }
  int rbase = blockIdx.x * 32;
  for (int i = threadIdx.x; i < 32 * KP; i += 512) {
    int row = i / KP, k = i - row * KP;
    int r = rbase + row; if (r >= n) r = n - 1;
    Xl[i] = (k < FA) ? xa[(size_t)r * FA + k] : xb[(size_t)r * 64 + (k - FA)];
  }
  __syncthreads();
  int lane = threadIdx.x & 63, w = threadIdx.x >> 6;
  int rb = rbase + w * 4;
  if (rb >= n) return;
  float alr = al[lane], arr_ = ar[lane];
  float alz = al[64 + lane], arz = ar[64 + lane];
  float accr[4], accz[4];
#pragma unroll
  for (int i = 0; i < 4; i++) { accr[i] = 0.f; accz[i] = 0.f; }
  const int xoff = (w * 4) * KP;
#pragma unroll 8
  for (int k = 0; k < KP; k += 2) {
    float2 w0 = *(const float2*)&Wl[(k * 64 + lane) * 2];
    float2 w1 = *(const float2*)&Wl[((k + 1) * 64 + lane) * 2];
#pragma unroll
    for (int i = 0; i < 4; i++) {
      float2 xv = *(const float2*)&Xl[xoff + i * KP + k];
      accr[i] = fmaf(xv.x, w0.x, accr[i]);
      accz[i] = fmaf(xv.x, w0.y, accz[i]);
      accr[i] = fmaf(xv.y, w1.x, accr[i]);
      accz[i] = fmaf(xv.y, w1.y, accz[i]);
    }
  }
#pragma unroll
  for (int i = 0; i < 4; i++) {
    int r = rb + i;
    bool ok = r < n;
    if (ok) {
      hb[(size_t)r * 128 + lane] = accr[i];
      hb[(size_t)r * 128 + 64 + lane] = accz[i];
    }
    float s0 = wsum64(accr[i] * alr);
    float s1 = wsum64(accz[i] * alz);
    float s2 = wsum64(accr[i] * arr_);
    float s3 = wsum64(accz[i] * arz);
    if (ok && lane == 0) {
      el[(size_t)r * 2 + 0] = s0;
      el[(size_t)r * 2 + 1] = s1;
      er[(size_t)r * 2 + 0] = s2;
      er[(size_t)r * 2 + 1] = s3;
    }
  }
}

// ---------------- K_B: agg r,z + fused candidate mm (shuffle MM1, proven) ----------------
template <int FA>
__global__ __launch_bounds__(512) void kb_k(
    const int* __restrict__ rp, const int* __restrict__ srcs,
    const float* __restrict__ hbuf, const float* __restrict__ elrz,
    const float* __restrict__ errz, const float* __restrict__ b,
    const float* __restrict__ xa, const float* __restrict__ hx,
    const float* __restrict__ Wc, const float* __restrict__ alc,
    const float* __restrict__ arc,
    float* __restrict__ hc, float* __restrict__ elc, float* __restrict__ erc,
    float* __restrict__ zb, int n) {
  constexpr int KP = FA + 64;
  __shared__ float WlC[KP * 64];
  for (int i = threadIdx.x; i < KP * 64; i += 512) {
    int k = i >> 6, c = i & 63;
    int ks = (k < 64) ? (FA + k) : (k - 64);   // [hx-part | xa-part] row order
    WlC[i] = Wc[(size_t)ks * 64 + c];
  }
  __syncthreads();
  int l16 = threadIdx.x & 15;
  int d = blockIdx.x * 32 + (threadIdx.x >> 4);
  if (d >= n) return;
  int beg = rp[d], deg = rp[d + 1] - beg;
  float2 erd = ((const float2*)errz)[d];
  const float4* h4 = (const float4*)hbuf;
  float4 accr = {0, 0, 0, 0}, accz = {0, 0, 0, 0};
  float sr = 0.f, sz = 0.f;
  for (int base = 0; base < deg; base += 16) {
    int k = base + l16;
    int s = 0;
    float exr = 0.f, exz = 0.f;
    if (k < deg) {
      s = srcs[beg + k];
      float2 el = ((const float2*)elrz)[s];
      exr = __expf(lrelu(el.x + erd.x));
      exz = __expf(lrelu(el.y + erd.y));
      sr += exr; sz += exz;
    }
#pragma unroll
    for (int j = 0; j < 16; j++) {
      int sj = __shfl(s, j, 16);
      float aj = __shfl(exr, j, 16);
      float zj = __shfl(exz, j, 16);
      float4 hr = h4[(size_t)sj * 32 + l16];
      float4 hz = h4[(size_t)sj * 32 + 16 + l16];
      accr.x = fmaf(aj, hr.x, accr.x); accr.y = fmaf(aj, hr.y, accr.y);
      accr.z = fmaf(aj, hr.z, accr.z); accr.w = fmaf(aj, hr.w, accr.w);
      accz.x = fmaf(zj, hz.x, accz.x); accz.y = fmaf(zj, hz.y, accz.y);
      accz.z = fmaf(zj, hz.z, accz.z); accz.w = fmaf(zj, hz.w, accz.w);
    }
  }
  sr = gsum16(sr); sz = gsum16(sz);
  float invr = 1.f / fmaxf(sr, 1e-9f);
  float invz = 1.f / fmaxf(sz, 1e-9f);
  float4 br4 = ((const float4*)b)[l16];
  float4 bz4 = ((const float4*)(b + 64))[l16];
  float4 hx4 = ((const float4*)hx)[(size_t)d * 16 + l16];
  float4 rv, zv;
  rv.x = sigf(fmaf(accr.x, invr, br4.x)) * hx4.x;
  rv.y = sigf(fmaf(accr.y, invr, br4.y)) * hx4.y;
  rv.z = sigf(fmaf(accr.z, invr, br4.z)) * hx4.z;
  rv.w = sigf(fmaf(accr.w, invr, br4.w)) * hx4.w;
  zv.x = sigf(fmaf(accz.x, invz, bz4.x));
  zv.y = sigf(fmaf(accz.y, invz, bz4.y));
  zv.z = sigf(fmaf(accz.z, invz, bz4.z));
  zv.w = sigf(fmaf(accz.w, invz, bz4.w));
  ((float4*)zb)[(size_t)d * 16 + l16] = zv;
  // fused mm_c
  const float4* W4 = (const float4*)WlC;
  float4 acc = {0, 0, 0, 0};
#pragma unroll
  for (int o = 0; o < 16; o++) {
    float f0 = __shfl(rv.x, o, 16);
    float f1 = __shfl(rv.y, o, 16);
    float f2 = __shfl(rv.z, o, 16);
    float f3 = __shfl(rv.w, o, 16);
    MM1(f0, 4 * o + 0); MM1(f1, 4 * o + 1);
    MM1(f2, 4 * o + 2); MM1(f3, 4 * o + 3);
  }
  if (FA == 2) {
    float f0 = xa[(size_t)d * 2 + 0];
    float f1 = xa[(size_t)d * 2 + 1];
    MM1(f0, 64); MM1(f1, 65);
  } else {
    float4 xv = ((const float4*)xa)[(size_t)d * 16 + l16];
#pragma unroll
    for (int o = 0; o < 16; o++) {
      float f0 = __shfl(xv.x, o, 16);
      float f1 = __shfl(xv.y, o, 16);
      float f2 = __shfl(xv.z, o, 16);
      float f3 = __shfl(xv.w, o, 16);
      MM1(f0, 64 + 4 * o + 0); MM1(f1, 64 + 4 * o + 1);
      MM1(f2, 64 + 4 * o + 2); MM1(f3, 64 + 4 * o + 3);
    }
  }
  float4 alv = ((const float4*)alc)[l16];
  float4 arv = ((const float4*)arc)[l16];
  float sl = gsum16(dp4(acc, alv));
  float sr2 = gsum16(dp4(acc, arv));
  if (l16 == 0) { elc[d] = sl; erc[d] = sr2; }
  ((float4*)hc)[(size_t)d * 16 + l16] = acc;
}

// ---------------- K_C: agg candidate + state + proj + next mm_rz (LDS mm0-style) ----------------
template <int FAN, bool NEXT>
__global__ __launch_bounds__(512) void kc_k(
    const int* __restrict__ rp, const int* __restrict__ srcs,
    const float* __restrict__ hc, const float* __restrict__ elc,
    const float* __restrict__ erc, const float* __restrict__ bc,
    const float* __restrict__ zb, float* __restrict__ hstate,
    const float* __restrict__ projW, const float* __restrict__ projb,
    float* __restrict__ outp,
    const float* __restrict__ Wn, const float* __restrict__ aln,
    const float* __restrict__ arn, const float* __restrict__ xan,
    const float* __restrict__ hxn,
    float* __restrict__ hbn, float* __restrict__ elrzn, float* __restrict__ errzn,
    int n) {
  constexpr int KPN = FAN + 64;
  __shared__ float Xn[NEXT ? 32 * KPN : 1];
  __shared__ float Wl[NEXT ? (FAN == 2 ? KPN * 128 : KPN * 64) : 1];
  int tid = threadIdx.x;
  int rbase = blockIdx.x * 32;

  if constexpr (NEXT) {
    // stage hx part of X (global, old state) -- independent of agg phase
    for (int i = tid; i < 32 * 64; i += 512) {
      int row = i >> 6, j = i & 63;
      int r = rbase + row; if (r >= n) r = n - 1;
      Xn[row * KPN + FAN + j] = hxn[(size_t)r * 64 + j];
    }
    if (FAN == 2 && xan) {
      for (int i = tid; i < 64; i += 512) {
        int row = i >> 1, j = i & 1;
        int r = rbase + row; if (r >= n) r = n - 1;
        Xn[row * KPN + j] = xan[(size_t)r * 2 + j];
      }
    }
    if (FAN == 2) {
      for (int i = tid; i < KPN * 64; i += 512) {
        Wl[i * 2 + 0] = Wn[i];
        Wl[i * 2 + 1] = Wn[(size_t)KPN * 64 + i];
      }
    } else {
      for (int i = tid; i < KPN * 64; i += 512) Wl[i] = Wn[i];  // gate r
    }
  }

  // ---- agg candidate + state update (+ proj) ----
  int l16 = tid & 15;
  int drow = tid >> 4;
  int d = rbase + drow;
  bool act = d < n;
  int dc = act ? d : (n - 1);
  int beg = rp[dc], deg = rp[dc + 1] - beg;
  float erd = erc[dc];
  const float4* h4 = (const float4*)hc;
  float4 acc = {0, 0, 0, 0};
  float ssum = 0.f;
  for (int base0 = 0; base0 < deg; base0 += 16) {
    int k = base0 + l16;
    int s = 0;
    float ex = 0.f;
    if (k < deg) {
      s = srcs[beg + k];
      ex = __expf(lrelu(elc[s] + erd));
      ssum += ex;
    }
#pragma unroll
    for (int j = 0; j < 16; j++) {
      int sj = __shfl(s, j, 16);
      float aj = __shfl(ex, j, 16);
      float4 hv = h4[(size_t)sj * 16 + l16];
      acc.x = fmaf(aj, hv.x, acc.x); acc.y = fmaf(aj, hv.y, acc.y);
      acc.z = fmaf(aj, hv.z, acc.z); acc.w = fmaf(aj, hv.w, acc.w);
    }
  }
  ssum = gsum16(ssum);
  float inv = 1.f / fmaxf(ssum, 1e-9f);
  float4 bc4 = ((const float4*)bc)[l16];
  float4 z4 = ((const float4*)zb)[(size_t)dc * 16 + l16];
  float4 hx4 = ((const float4*)hstate)[(size_t)dc * 16 + l16];
  float4 hcv, hn;
  hcv.x = tanhf(fmaf(acc.x, inv, bc4.x));
  hcv.y = tanhf(fmaf(acc.y, inv, bc4.y));
  hcv.z = tanhf(fmaf(acc.z, inv, bc4.z));
  hcv.w = tanhf(fmaf(acc.w, inv, bc4.w));
  hn.x = z4.x * hx4.x + (1.f - z4.x) * hcv.x;
  hn.y = z4.y * hx4.y + (1.f - z4.y) * hcv.y;
  hn.z = z4.z * hx4.z + (1.f - z4.z) * hcv.z;
  hn.w = z4.w * hx4.w + (1.f - z4.w) * hcv.w;
  if (act) ((float4*)hstate)[(size_t)d * 16 + l16] = hn;
  float p0 = 0.f, p1 = 0.f;
  if (outp) {
    const float4* wp4 = (const float4*)projW;   // [64][2] row-major
    float4 a0 = wp4[l16 * 2], a1 = wp4[l16 * 2 + 1];
    p0 = gsum16(hn.x * a0.x + hn.y * a0.z + hn.z * a1.x + hn.w * a1.z) + projb[0];
    p1 = gsum16(hn.x * a0.y + hn.y * a0.w + hn.z * a1.y + hn.w * a1.w) + projb[1];
    if (act && l16 == 0) {
      outp[(size_t)d * 2 + 0] = p0;
      outp[(size_t)d * 2 + 1] = p1;
    }
  }

  if constexpr (NEXT) {
    // local parts of X
    if (FAN == 64) {
      *(float4*)&Xn[drow * KPN + l16 * 4] = hn;     // xa = new state (this layer)
    } else {
      if (!xan && l16 == 0) {                        // decoder pred chain
        Xn[drow * KPN + 0] = p0;
        Xn[drow * KPN + 1] = p1;
      }
    }
    __syncthreads();
    int lane = tid & 63, w = tid >> 6;
    int rb = rbase + w * 4;
    const int xoff = (w * 4) * KPN;
    if (FAN == 2) {
      float ar_[4], az_[4];
#pragma unroll
      for (int i = 0; i < 4; i++) { ar_[i] = 0.f; az_[i] = 0.f; }
#pragma unroll 3
      for (int k = 0; k < KPN; k += 2) {
        float2 w0 = *(const float2*)&Wl[(k * 64 + lane) * 2];
        float2 w1 = *(const float2*)&Wl[((k + 1) * 64 + lane) * 2];
#pragma unroll
        for (int i = 0; i < 4; i++) {
          float2 xv = *(const float2*)&Xn[xoff + i * KPN + k];
          ar_[i] = fmaf(xv.x, w0.x, ar_[i]);
          az_[i] = fmaf(xv.x, w0.y, az_[i]);
          ar_[i] = fmaf(xv.y, w1.x, ar_[i]);
          az_[i] = fmaf(xv.y, w1.y, az_[i]);
        }
      }
      float alr = aln[lane], alz = aln[64 + lane];
      float arr2 = arn[lane], arz = arn[64 + lane];
#pragma unroll
      for (int i = 0; i < 4; i++) {
        int r = rb + i;
        bool ok = r < n;
        if (ok) {
          hbn[(size_t)r * 128 + lane] = ar_[i];
          hbn[(size_t)r * 128 + 64 + lane] = az_[i];
        }
        float e0 = wsum64(ar_[i] * alr);
        float e1 = wsum64(az_[i] * alz);
        float e2 = wsum64(ar_[i] * arr2);
        float e3 = wsum64(az_[i] * arz);
        if (ok && lane == 0) {
          elrzn[(size_t)r * 2 + 0] = e0;
          elrzn[(size_t)r * 2 + 1] = e1;
          errzn[(size_t)r * 2 + 0] = e2;
          errzn[(size_t)r * 2 + 1] = e3;
        }
      }
    } else {
      // pass 1: gate r
      float ac[4];
#pragma unroll
      for (int i = 0; i < 4; i++) ac[i] = 0.f;
#pragma unroll 8
      for (int k = 0; k < KPN; k += 2) {
        float w0 = Wl[k * 64 + lane];
        float w1 = Wl[(k + 1) * 64 + lane];
#pragma unroll
        for (int i = 0; i < 4; i++) {
          float2 xv = *(const float2*)&Xn[xoff + i * KPN + k];
          ac[i] = fmaf(xv.x, w0, ac[i]);
          ac[i] = fmaf(xv.y, w1, ac[i]);
        }
      }
      {
        float alr = aln[lane], arr2 = arn[lane];
#pragma unroll
        for (int i = 0; i < 4; i++) {
          int r = rb + i;
          bool ok = r < n;
          if (ok) hbn[(size_t)r * 128 + lane] = ac[i];
          float e0 = wsum64(ac[i] * alr);
          float e2 = wsum64(ac[i] * arr2);
          if (ok && lane == 0) {
            elrzn[(size_t)r * 2 + 0] = e0;
            errzn[(size_t)r * 2 + 0] = e2;
          }
        }
      }
      __syncthreads();
      for (int i = tid; i < KPN * 64; i += 512) Wl[i] = Wn[(size_t)KPN * 64 + i];  // gate z
      __syncthreads();
#pragma unroll
      for (int i = 0; i < 4; i++) ac[i] = 0.f;
#pragma unroll 8
      for (int k = 0; k < KPN; k += 2) {
        float w0 = Wl[k * 64 + lane];
        float w1 = Wl[(k + 1) * 64 + lane];
#pragma unroll
        for (int i = 0; i < 4; i++) {
          float2 xv = *(const float2*)&Xn[xoff + i * KPN + k];
          ac[i] = fmaf(xv.x, w0, ac[i]);
          ac[i] = fmaf(xv.y, w1, ac[i]);
        }
      }
      {
        float alz = aln[64 + lane], arz = arn[64 + lane];
#pragma unroll
        for (int i = 0; i < 4; i++) {
          int r = rb + i;
          bool ok = r < n;
          if (ok) hbn[(size_t)r * 128 + 64 + lane] = ac[i];
          float e1 = wsum64(ac[i] * alz);
          float e3 = wsum64(ac[i] * arz);
          if (ok && lane == 0) {
            elrzn[(size_t)r * 2 + 1] = e1;
            errzn[(size_t)r * 2 + 1] = e3;
          }
        }
      }
    }
  }
}

extern "C" void kernel_launch(void* const* d_in, const int* in_sizes, int n_in,
                              void* d_out, int out_size, void* d_ws, size_t ws_size,
                              hipStream_t stream) {
  const int T = 12, F = 2, H = 64;
  const float* x = (const float*)d_in[0];
  const int* src = (const int*)d_in[1];
  const int* dst = (const int*)d_in[2];
  const float* Ws[4] = {(const float*)d_in[3], (const float*)d_in[7],
                        (const float*)d_in[11], (const float*)d_in[15]};
  const float* als[4] = {(const float*)d_in[4], (const float*)d_in[8],
                         (const float*)d_in[12], (const float*)d_in[16]};
  const float* ars[4] = {(const float*)d_in[5], (const float*)d_in[9],
                         (const float*)d_in[13], (const float*)d_in[17]};
  const float* bs[4] = {(const float*)d_in[6], (const float*)d_in[10],
                        (const float*)d_in[14], (const float*)d_in[18]};
  const float* proj_W = (const float*)d_in[19];
  const float* proj_b = (const float*)d_in[20];
  float* out = (float*)d_out;

  const int E = in_sizes[1];
  const int N = in_sizes[0] / (T * F);
  const int NB = (N + 1023) / 1024;

  char* wp = (char*)d_ws;
  size_t off = 0;
  auto carve = [&](size_t bytes) {
    void* p = wp + off;
    off = (off + bytes + 255) & ~(size_t)255;
    return p;
  };
  int* counts = (int*)carve((size_t)N * 4);
  int* bsum = (int*)carve((size_t)NB * 4);
  int* rp = (int*)carve((size_t)(N + 1) * 4);
  int* cursor = (int*)carve((size_t)N * 4);
  int* srcs = (int*)carve((size_t)E * 4);
  float* hs0 = (float*)carve((size_t)N * H * 4);
  float* hs1 = (float*)carve((size_t)N * H * 4);
  float* hbuf = (float*)carve((size_t)N * 2 * H * 4);
  float* elrz = (float*)carve((size_t)N * 2 * 4);
  float* errz = (float*)carve((size_t)N * 2 * 4);
  float* hcb = (float*)carve((size_t)N * H * 4);
  float* elc = (float*)carve((size_t)N * 4);
  float* erc = (float*)carve((size_t)N * 4);
  float* zbuf = (float*)carve((size_t)N * H * 4);
  float* zero2 = (float*)carve((size_t)N * F * 4);
  (void)ws_size;

  const int G_E = (E + 255) / 256;
  const int G32 = (N + 31) / 32;

  // ---- CSR by destination ----
  hipMemsetAsync(counts, 0, (size_t)N * 4, stream);
  hist_k<<<G_E, 256, 0, stream>>>(dst, counts, E);
  bsum_k<<<NB, 256, 0, stream>>>(counts, bsum, N);
  scan_bsum_k<<<1, 1024, 0, stream>>>(bsum, rp + N, NB);
  scan_fin_k<<<NB, 1024, 0, stream>>>(counts, bsum, rp, cursor, N);
  scatter_k<<<G_E, 256, 0, stream>>>(src, dst, cursor, srcs, E);

  // ---- init states ----
  hipMemsetAsync(hs0, 0, (size_t)N * H * 4, stream);
  hipMemsetAsync(hs1, 0, (size_t)N * H * 4, stream);
  hipMemsetAsync(zero2, 0, (size_t)N * F * 4, stream);

  // ---- initial r,z dense for enc layer0 t=0 ----
  mm0_k<2><<<G32, 512, 0, stream>>>(x, hs0, Ws[0], als[0], ars[0], hbuf, elrz, errz, N);

  // ---- 48 GRU cells, 2 kernels each ----
  for (int i = 0; i < 48; i++) {
    bool enc = i < 24;
    int j = enc ? i : i - 24;
    int t = j >> 1, layer = j & 1;
    int type = (enc ? 0 : 2) + layer;
    const float* W = Ws[type];
    const float* al = als[type];
    const float* ar = ars[type];
    const float* b = bs[type];
    int FA = layer ? 64 : 2;
    size_t KP = FA + 64;
    const float* Wc = W + (size_t)2 * KP * 64;
    const float* xa = layer ? hs0
                            : (enc ? x + (size_t)t * N * 2
                                   : (t == 0 ? zero2 : out + (size_t)(t - 1) * N * 2));
    float* hstate = layer ? hs1 : hs0;
    float* outp = (!enc && layer) ? out + (size_t)t * N * 2 : nullptr;

    if (FA == 2)
      kb_k<2><<<G32, 512, 0, stream>>>(rp, srcs, hbuf, elrz, errz, b, xa, hstate,
                                       Wc, al + 128, ar + 128, hcb, elc, erc, zbuf, N);
    else
      kb_k<64><<<G32, 512, 0, stream>>>(rp, srcs, hbuf, elrz, errz, b, xa, hstate,
                                        Wc, al + 128, ar + 128, hcb, elc, erc, zbuf, N);

    if (i == 47) {
      kc_k<2, false><<<G32, 512, 0, stream>>>(
          rp, srcs, hcb, elc, erc, b + 128, zbuf, hstate, proj_W, proj_b, outp,
          nullptr, nullptr, nullptr, nullptr, nullptr, nullptr, nullptr, nullptr, N);
    } else {
      int i2 = i + 1;
      bool enc2 = i2 < 24;
      int j2 = enc2 ? i2 : i2 - 24;
      int t2 = j2 >> 1, l2 = j2 & 1;
      int type2 = (enc2 ? 0 : 2) + l2;
      const float* Wn = Ws[type2];
      const float* aln = als[type2];
      const float* arn = ars[type2];
      const float* xan = nullptr;
      if (l2 == 0) {
        if (enc2) xan = x + (size_t)t2 * N * 2;   // next encoder layer0
        else if (t2 == 0) xan = zero2;            // first decoder step
        // else: decoder pred chain -> local p0,p1
      }
      const float* hxn = l2 ? hs1 : hs0;          // next cell's (old) hidden state
      if (l2)
        kc_k<64, true><<<G32, 512, 0, stream>>>(
            rp, srcs, hcb, elc, erc, b + 128, zbuf, hstate, proj_W, proj_b, outp,
            Wn, aln, arn, xan, hxn, hbuf, elrz, errz, N);
      else
        kc_k<2, true><<<G32, 512, 0, stream>>>(
            rp, srcs, hcb, elc, erc, b + 128, zbuf, hstate, proj_W, proj_b, outp,
            Wn, aln, arn, xan, hxn, hbuf, elrz, errz, N);
    }
  }
  (void)out_size; (void)n_in;
}

// Round 8
// 7560.163 us; speedup vs baseline: 4.0473x; 1.0656x over previous
//
#include <hip/hip_runtime.h>
#include <hip/hip_bf16.h>

__device__ __forceinline__ float wsum64(float v) {
#pragma unroll
  for (int m = 32; m > 0; m >>= 1) v += __shfl_xor(v, m, 64);
  return v;
}
__device__ __forceinline__ float gsum16(float v) {
#pragma unroll
  for (int m = 8; m > 0; m >>= 1) v += __shfl_xor(v, m, 16);
  return v;
}
__device__ __forceinline__ float lrelu(float x) { return x > 0.f ? x : 0.2f * x; }
__device__ __forceinline__ float sigf(float x) { return 1.f / (1.f + __expf(-x)); }
__device__ __forceinline__ float dp4(float4 a, float4 b) {
  return a.x * b.x + a.y * b.y + a.z * b.z + a.w * b.w;
}

#define MM1(f, row)                                        \
  {                                                        \
    float4 w_ = W4[(row) * 16 + l16];                      \
    acc.x = fmaf((f), w_.x, acc.x);                        \
    acc.y = fmaf((f), w_.y, acc.y);                        \
    acc.z = fmaf((f), w_.z, acc.z);                        \
    acc.w = fmaf((f), w_.w, acc.w);                        \
  }

// ---------------- CSR build ----------------
__global__ void hist_k(const int* __restrict__ dst, int* __restrict__ cnt, int e) {
  int i = blockIdx.x * blockDim.x + threadIdx.x;
  if (i < e) atomicAdd(&cnt[dst[i]], 1);
}

__global__ __launch_bounds__(256) void bsum_k(const int* __restrict__ cnt,
                                              int* __restrict__ bsum, int n) {
  __shared__ int red[4];
  int base = blockIdx.x * 1024;
  int t = threadIdx.x;
  int v = 0;
#pragma unroll
  for (int i = 0; i < 4; i++) {
    int idx = base + t + i * 256;
    v += (idx < n) ? cnt[idx] : 0;
  }
#pragma unroll
  for (int m = 32; m > 0; m >>= 1) v += __shfl_xor(v, m, 64);
  if ((t & 63) == 0) red[t >> 6] = v;
  __syncthreads();
  if (t == 0) bsum[blockIdx.x] = red[0] + red[1] + red[2] + red[3];
}

__global__ __launch_bounds__(1024) void scan_bsum_k(int* __restrict__ bsum,
                                                    int* __restrict__ rpn, int nb) {
  __shared__ int buf[1024];
  int t = threadIdx.x;
  int v = (t < nb) ? bsum[t] : 0;
  buf[t] = v;
  __syncthreads();
  int val = v;
  for (int off = 1; off < 1024; off <<= 1) {
    int u = (t >= off) ? buf[t - off] : 0;
    __syncthreads();
    val += u;
    buf[t] = val;
    __syncthreads();
  }
  if (t < nb) bsum[t] = val - v;
  if (t == nb - 1) *rpn = val;
}

__global__ __launch_bounds__(1024) void scan_fin_k(const int* __restrict__ cnt,
                                                   const int* __restrict__ bsum,
                                                   int* __restrict__ rp,
                                                   int* __restrict__ cursor, int n) {
  __shared__ int buf[1024];
  int t = threadIdx.x;
  int idx = blockIdx.x * 1024 + t;
  int v = (idx < n) ? cnt[idx] : 0;
  buf[t] = v;
  __syncthreads();
  int val = v;
  for (int off = 1; off < 1024; off <<= 1) {
    int u = (t >= off) ? buf[t - off] : 0;
    __syncthreads();
    val += u;
    buf[t] = val;
    __syncthreads();
  }
  if (idx < n) {
    int e = bsum[blockIdx.x] + val - v;
    rp[idx] = e;
    cursor[idx] = e;
  }
}

__global__ void scatter_k(const int* __restrict__ src, const int* __restrict__ dst,
                          int* __restrict__ cursor, int* __restrict__ srcs, int e) {
  int i = blockIdx.x * blockDim.x + threadIdx.x;
  if (i < e) {
    int pos = atomicAdd(&cursor[dst[i]], 1);
    srcs[pos] = src[i];
  }
}

// ---------------- standalone mm for the very first r,z gates ----------------
template <int FA>
__global__ __launch_bounds__(512) void mm0_k(
    const float* __restrict__ xa, const float* __restrict__ xb,
    const float* __restrict__ Wg, const float* __restrict__ al, const float* __restrict__ ar,
    float* __restrict__ hb, float* __restrict__ el, float* __restrict__ er, int n) {
  constexpr int KP = FA + 64;
  __shared__ float Wl[KP * 128];
  __shared__ float Xl[32 * KP];
  for (int i = threadIdx.x; i < KP * 64; i += 512) {
    float2 wv = {Wg[i], Wg[(size_t)KP * 64 + i]};
    *(float2*)&Wl[i * 2] = wv;
  }
  int rbase = blockIdx.x * 32;
  for (int i = threadIdx.x; i < 32 * KP; i += 512) {
    int row = i / KP, k = i - row * KP;
    int r = rbase + row; if (r >= n) r = n - 1;
    Xl[i] = (k < FA) ? xa[(size_t)r * FA + k] : xb[(size_t)r * 64 + (k - FA)];
  }
  __syncthreads();
  int lane = threadIdx.x & 63, w = threadIdx.x >> 6;
  int rb = rbase + w * 4;
  if (rb >= n) return;
  float alr = al[lane], arr_ = ar[lane];
  float alz = al[64 + lane], arz = ar[64 + lane];
  float accr[4], accz[4];
#pragma unroll
  for (int i = 0; i < 4; i++) { accr[i] = 0.f; accz[i] = 0.f; }
  const int xoff = (w * 4) * KP;
#pragma unroll 8
  for (int k = 0; k < KP; k += 2) {
    float2 w0 = *(const float2*)&Wl[(k * 64 + lane) * 2];
    float2 w1 = *(const float2*)&Wl[((k + 1) * 64 + lane) * 2];
#pragma unroll
    for (int i = 0; i < 4; i++) {
      float2 xv = *(const float2*)&Xl[xoff + i * KP + k];
      accr[i] = fmaf(xv.x, w0.x, accr[i]);
      accz[i] = fmaf(xv.x, w0.y, accz[i]);
      accr[i] = fmaf(xv.y, w1.x, accr[i]);
      accz[i] = fmaf(xv.y, w1.y, accz[i]);
    }
  }
#pragma unroll
  for (int i = 0; i < 4; i++) {
    int r = rb + i;
    bool ok = r < n;
    if (ok) {
      hb[(size_t)r * 128 + lane] = accr[i];
      hb[(size_t)r * 128 + 64 + lane] = accz[i];
    }
    float s0 = wsum64(accr[i] * alr);
    float s1 = wsum64(accz[i] * alz);
    float s2 = wsum64(accr[i] * arr_);
    float s3 = wsum64(accz[i] * arz);
    if (ok && lane == 0) {
      el[(size_t)r * 2 + 0] = s0;
      el[(size_t)r * 2 + 1] = s1;
      er[(size_t)r * 2 + 0] = s2;
      er[(size_t)r * 2 + 1] = s3;
    }
  }
}

// ---------------- K_B: agg r,z + fused candidate mm (shuffle MM1, proven) ----------------
template <int FA>
__global__ __launch_bounds__(512) void kb_k(
    const int* __restrict__ rp, const int* __restrict__ srcs,
    const float* __restrict__ hbuf, const float* __restrict__ elrz,
    const float* __restrict__ errz, const float* __restrict__ b,
    const float* __restrict__ xa, const float* __restrict__ hx,
    const float* __restrict__ Wc, const float* __restrict__ alc,
    const float* __restrict__ arc,
    float* __restrict__ hc, float* __restrict__ elc, float* __restrict__ erc,
    float* __restrict__ zb, int n) {
  constexpr int KP = FA + 64;
  __shared__ float WlC[KP * 64];
  for (int i = threadIdx.x; i < KP * 64; i += 512) {
    int k = i >> 6, c = i & 63;
    int ks = (k < 64) ? (FA + k) : (k - 64);   // [hx-part | xa-part] row order
    WlC[i] = Wc[(size_t)ks * 64 + c];
  }
  __syncthreads();
  int l16 = threadIdx.x & 15;
  int d = blockIdx.x * 32 + (threadIdx.x >> 4);
  if (d >= n) return;
  int beg = rp[d], deg = rp[d + 1] - beg;
  float2 erd = ((const float2*)errz)[d];
  const float4* h4 = (const float4*)hbuf;
  float4 accr = {0, 0, 0, 0}, accz = {0, 0, 0, 0};
  float sr = 0.f, sz = 0.f;
  for (int base = 0; base < deg; base += 16) {
    int k = base + l16;
    int s = 0;
    float exr = 0.f, exz = 0.f;
    if (k < deg) {
      s = srcs[beg + k];
      float2 el = ((const float2*)elrz)[s];
      exr = __expf(lrelu(el.x + erd.x));
      exz = __expf(lrelu(el.y + erd.y));
      sr += exr; sz += exz;
    }
#pragma unroll
    for (int j = 0; j < 16; j++) {
      int sj = __shfl(s, j, 16);
      float aj = __shfl(exr, j, 16);
      float zj = __shfl(exz, j, 16);
      float4 hr = h4[(size_t)sj * 32 + l16];
      float4 hz = h4[(size_t)sj * 32 + 16 + l16];
      accr.x = fmaf(aj, hr.x, accr.x); accr.y = fmaf(aj, hr.y, accr.y);
      accr.z = fmaf(aj, hr.z, accr.z); accr.w = fmaf(aj, hr.w, accr.w);
      accz.x = fmaf(zj, hz.x, accz.x); accz.y = fmaf(zj, hz.y, accz.y);
      accz.z = fmaf(zj, hz.z, accz.z); accz.w = fmaf(zj, hz.w, accz.w);
    }
  }
  sr = gsum16(sr); sz = gsum16(sz);
  float invr = 1.f / fmaxf(sr, 1e-9f);
  float invz = 1.f / fmaxf(sz, 1e-9f);
  float4 br4 = ((const float4*)b)[l16];
  float4 bz4 = ((const float4*)(b + 64))[l16];
  float4 hx4 = ((const float4*)hx)[(size_t)d * 16 + l16];
  float4 rv, zv;
  rv.x = sigf(fmaf(accr.x, invr, br4.x)) * hx4.x;
  rv.y = sigf(fmaf(accr.y, invr, br4.y)) * hx4.y;
  rv.z = sigf(fmaf(accr.z, invr, br4.z)) * hx4.z;
  rv.w = sigf(fmaf(accr.w, invr, br4.w)) * hx4.w;
  zv.x = sigf(fmaf(accz.x, invz, bz4.x));
  zv.y = sigf(fmaf(accz.y, invz, bz4.y));
  zv.z = sigf(fmaf(accz.z, invz, bz4.z));
  zv.w = sigf(fmaf(accz.w, invz, bz4.w));
  ((float4*)zb)[(size_t)d * 16 + l16] = zv;
  // fused mm_c
  const float4* W4 = (const float4*)WlC;
  float4 acc = {0, 0, 0, 0};
#pragma unroll
  for (int o = 0; o < 16; o++) {
    float f0 = __shfl(rv.x, o, 16);
    float f1 = __shfl(rv.y, o, 16);
    float f2 = __shfl(rv.z, o, 16);
    float f3 = __shfl(rv.w, o, 16);
    MM1(f0, 4 * o + 0); MM1(f1, 4 * o + 1);
    MM1(f2, 4 * o + 2); MM1(f3, 4 * o + 3);
  }
  if (FA == 2) {
    float f0 = xa[(size_t)d * 2 + 0];
    float f1 = xa[(size_t)d * 2 + 1];
    MM1(f0, 64); MM1(f1, 65);
  } else {
    float4 xv = ((const float4*)xa)[(size_t)d * 16 + l16];
#pragma unroll
    for (int o = 0; o < 16; o++) {
      float f0 = __shfl(xv.x, o, 16);
      float f1 = __shfl(xv.y, o, 16);
      float f2 = __shfl(xv.z, o, 16);
      float f3 = __shfl(xv.w, o, 16);
      MM1(f0, 64 + 4 * o + 0); MM1(f1, 64 + 4 * o + 1);
      MM1(f2, 64 + 4 * o + 2); MM1(f3, 64 + 4 * o + 3);
    }
  }
  float4 alv = ((const float4*)alc)[l16];
  float4 arv = ((const float4*)arc)[l16];
  float sl = gsum16(dp4(acc, alv));
  float sr2 = gsum16(dp4(acc, arv));
  if (l16 == 0) { elc[d] = sl; erc[d] = sr2; }
  ((float4*)hc)[(size_t)d * 16 + l16] = acc;
}

// ---------------- K_C: agg candidate + state + proj + next mm_rz (shuffle, barrier-free) ----
template <int FAN, bool NEXT>
__global__ __launch_bounds__(512) void kc_k(
    const int* __restrict__ rp, const int* __restrict__ srcs,
    const float* __restrict__ hc, const float* __restrict__ elc,
    const float* __restrict__ erc, const float* __restrict__ bc,
    const float* __restrict__ zb, float* __restrict__ hstate,
    const float* __restrict__ projW, const float* __restrict__ projb,
    float* __restrict__ outp,
    const float* __restrict__ Wn, const float* __restrict__ aln,
    const float* __restrict__ arn, const float* __restrict__ xan,
    const float* __restrict__ hxn,
    float* __restrict__ hbn, float* __restrict__ elrzn, float* __restrict__ errzn,
    int n) {
  constexpr int KPN = FAN + 64;
  __shared__ float Wl[NEXT ? 2 * KPN * 64 : 1];   // [gate][row(hx|xa)][col]
  int tid = threadIdx.x;
  int rbase = blockIdx.x * 32;

  if constexpr (NEXT) {
    // stage BOTH gates' W, permuted rows [hx | xa]; single barrier, before agg.
    for (int i = tid; i < 2 * KPN * 64; i += 512) {
      int g = i / (KPN * 64);
      int idx = i - g * KPN * 64;
      int k = idx >> 6, c = idx & 63;
      int ks = (k < 64) ? (FAN + k) : (k - 64);
      Wl[i] = Wn[((size_t)g * KPN + ks) * 64 + c];
    }
    __syncthreads();
  }

  // ---- agg candidate + state update (+ proj) ----
  int l16 = tid & 15;
  int drow = tid >> 4;
  int d = rbase + drow;
  bool act = d < n;
  int dc = act ? d : (n - 1);
  int beg = rp[dc], deg = rp[dc + 1] - beg;
  float erd = erc[dc];
  const float4* h4 = (const float4*)hc;
  float4 acg = {0, 0, 0, 0};
  float ssum = 0.f;
  for (int base0 = 0; base0 < deg; base0 += 16) {
    int k = base0 + l16;
    int s = 0;
    float ex = 0.f;
    if (k < deg) {
      s = srcs[beg + k];
      ex = __expf(lrelu(elc[s] + erd));
      ssum += ex;
    }
#pragma unroll
    for (int j = 0; j < 16; j++) {
      int sj = __shfl(s, j, 16);
      float aj = __shfl(ex, j, 16);
      float4 hv = h4[(size_t)sj * 16 + l16];
      acg.x = fmaf(aj, hv.x, acg.x); acg.y = fmaf(aj, hv.y, acg.y);
      acg.z = fmaf(aj, hv.z, acg.z); acg.w = fmaf(aj, hv.w, acg.w);
    }
  }
  ssum = gsum16(ssum);
  float inv = 1.f / fmaxf(ssum, 1e-9f);
  float4 bc4 = ((const float4*)bc)[l16];
  float4 z4 = ((const float4*)zb)[(size_t)dc * 16 + l16];
  float4 hx4 = ((const float4*)hstate)[(size_t)dc * 16 + l16];
  float4 hcv, hn;
  hcv.x = tanhf(fmaf(acg.x, inv, bc4.x));
  hcv.y = tanhf(fmaf(acg.y, inv, bc4.y));
  hcv.z = tanhf(fmaf(acg.z, inv, bc4.z));
  hcv.w = tanhf(fmaf(acg.w, inv, bc4.w));
  hn.x = z4.x * hx4.x + (1.f - z4.x) * hcv.x;
  hn.y = z4.y * hx4.y + (1.f - z4.y) * hcv.y;
  hn.z = z4.z * hx4.z + (1.f - z4.z) * hcv.z;
  hn.w = z4.w * hx4.w + (1.f - z4.w) * hcv.w;
  if (act) ((float4*)hstate)[(size_t)d * 16 + l16] = hn;
  float p0 = 0.f, p1 = 0.f;
  if (outp) {
    const float4* wp4 = (const float4*)projW;   // [64][2] row-major
    float4 a0 = wp4[l16 * 2], a1 = wp4[l16 * 2 + 1];
    p0 = gsum16(hn.x * a0.x + hn.y * a0.z + hn.z * a1.x + hn.w * a1.z) + projb[0];
    p1 = gsum16(hn.x * a0.y + hn.y * a0.w + hn.z * a1.y + hn.w * a1.w) + projb[1];
    if (act && l16 == 0) {
      outp[(size_t)d * 2 + 0] = p0;
      outp[(size_t)d * 2 + 1] = p1;
    }
  }

  if constexpr (NEXT) {
    // fused next-cell mm_rz: features in regs, W in LDS, no further barriers.
    float4 hxn4 = ((const float4*)hxn)[(size_t)dc * 16 + l16];
    float fa0 = 0.f, fa1 = 0.f;
    float4 xv = hn;   // FAN==64: xa = this kernel's new state (local)
    if (FAN == 2) {
      if (xan) { fa0 = xan[(size_t)dc * 2 + 0]; fa1 = xan[(size_t)dc * 2 + 1]; }
      else { fa0 = p0; fa1 = p1; }   // decoder pred chain (uniform in group)
    }
#pragma unroll
    for (int g = 0; g < 2; g++) {
      const float4* W4 = (const float4*)(Wl + g * KPN * 64);
      float4 acc = {0, 0, 0, 0};
#pragma unroll
      for (int o = 0; o < 16; o++) {           // hx rows 0..63
        float f0 = __shfl(hxn4.x, o, 16);
        float f1 = __shfl(hxn4.y, o, 16);
        float f2 = __shfl(hxn4.z, o, 16);
        float f3 = __shfl(hxn4.w, o, 16);
        MM1(f0, 4 * o + 0); MM1(f1, 4 * o + 1);
        MM1(f2, 4 * o + 2); MM1(f3, 4 * o + 3);
      }
      if (FAN == 2) {
        MM1(fa0, 64); MM1(fa1, 65);
      } else {
#pragma unroll
        for (int o = 0; o < 16; o++) {         // xa rows 64..127
          float f0 = __shfl(xv.x, o, 16);
          float f1 = __shfl(xv.y, o, 16);
          float f2 = __shfl(xv.z, o, 16);
          float f3 = __shfl(xv.w, o, 16);
          MM1(f0, 64 + 4 * o + 0); MM1(f1, 64 + 4 * o + 1);
          MM1(f2, 64 + 4 * o + 2); MM1(f3, 64 + 4 * o + 3);
        }
      }
      float4 al4 = ((const float4*)aln)[g * 16 + l16];
      float4 ar4 = ((const float4*)arn)[g * 16 + l16];
      float eL = gsum16(dp4(acc, al4));
      float eR = gsum16(dp4(acc, ar4));
      if (act && l16 == 0) {
        elrzn[(size_t)d * 2 + g] = eL;
        errzn[(size_t)d * 2 + g] = eR;
      }
      if (act) ((float4*)hbn)[(size_t)d * 32 + g * 16 + l16] = acc;
    }
  }
}

extern "C" void kernel_launch(void* const* d_in, const int* in_sizes, int n_in,
                              void* d_out, int out_size, void* d_ws, size_t ws_size,
                              hipStream_t stream) {
  const int T = 12, F = 2, H = 64;
  const float* x = (const float*)d_in[0];
  const int* src = (const int*)d_in[1];
  const int* dst = (const int*)d_in[2];
  const float* Ws[4] = {(const float*)d_in[3], (const float*)d_in[7],
                        (const float*)d_in[11], (const float*)d_in[15]};
  const float* als[4] = {(const float*)d_in[4], (const float*)d_in[8],
                         (const float*)d_in[12], (const float*)d_in[16]};
  const float* ars[4] = {(const float*)d_in[5], (const float*)d_in[9],
                         (const float*)d_in[13], (const float*)d_in[17]};
  const float* bs[4] = {(const float*)d_in[6], (const float*)d_in[10],
                        (const float*)d_in[14], (const float*)d_in[18]};
  const float* proj_W = (const float*)d_in[19];
  const float* proj_b = (const float*)d_in[20];
  float* out = (float*)d_out;

  const int E = in_sizes[1];
  const int N = in_sizes[0] / (T * F);
  const int NB = (N + 1023) / 1024;

  char* wp = (char*)d_ws;
  size_t off = 0;
  auto carve = [&](size_t bytes) {
    void* p = wp + off;
    off = (off + bytes + 255) & ~(size_t)255;
    return p;
  };
  int* counts = (int*)carve((size_t)N * 4);
  int* bsum = (int*)carve((size_t)NB * 4);
  int* rp = (int*)carve((size_t)(N + 1) * 4);
  int* cursor = (int*)carve((size_t)N * 4);
  int* srcs = (int*)carve((size_t)E * 4);
  float* hs0 = (float*)carve((size_t)N * H * 4);
  float* hs1 = (float*)carve((size_t)N * H * 4);
  float* hbuf = (float*)carve((size_t)N * 2 * H * 4);
  float* elrz = (float*)carve((size_t)N * 2 * 4);
  float* errz = (float*)carve((size_t)N * 2 * 4);
  float* hcb = (float*)carve((size_t)N * H * 4);
  float* elc = (float*)carve((size_t)N * 4);
  float* erc = (float*)carve((size_t)N * 4);
  float* zbuf = (float*)carve((size_t)N * H * 4);
  float* zero2 = (float*)carve((size_t)N * F * 4);
  (void)ws_size;

  const int G_E = (E + 255) / 256;
  const int G32 = (N + 31) / 32;

  // ---- CSR by destination ----
  hipMemsetAsync(counts, 0, (size_t)N * 4, stream);
  hist_k<<<G_E, 256, 0, stream>>>(dst, counts, E);
  bsum_k<<<NB, 256, 0, stream>>>(counts, bsum, N);
  scan_bsum_k<<<1, 1024, 0, stream>>>(bsum, rp + N, NB);
  scan_fin_k<<<NB, 1024, 0, stream>>>(counts, bsum, rp, cursor, N);
  scatter_k<<<G_E, 256, 0, stream>>>(src, dst, cursor, srcs, E);

  // ---- init states ----
  hipMemsetAsync(hs0, 0, (size_t)N * H * 4, stream);
  hipMemsetAsync(hs1, 0, (size_t)N * H * 4, stream);
  hipMemsetAsync(zero2, 0, (size_t)N * F * 4, stream);

  // ---- initial r,z dense for enc layer0 t=0 ----
  mm0_k<2><<<G32, 512, 0, stream>>>(x, hs0, Ws[0], als[0], ars[0], hbuf, elrz, errz, N);

  // ---- 48 GRU cells, 2 kernels each ----
  for (int i = 0; i < 48; i++) {
    bool enc = i < 24;
    int j = enc ? i : i - 24;
    int t = j >> 1, layer = j & 1;
    int type = (enc ? 0 : 2) + layer;
    const float* W = Ws[type];
    const float* al = als[type];
    const float* ar = ars[type];
    const float* b = bs[type];
    int FA = layer ? 64 : 2;
    size_t KP = FA + 64;
    const float* Wc = W + (size_t)2 * KP * 64;
    const float* xa = layer ? hs0
                            : (enc ? x + (size_t)t * N * 2
                                   : (t == 0 ? zero2 : out + (size_t)(t - 1) * N * 2));
    float* hstate = layer ? hs1 : hs0;
    float* outp = (!enc && layer) ? out + (size_t)t * N * 2 : nullptr;

    if (FA == 2)
      kb_k<2><<<G32, 512, 0, stream>>>(rp, srcs, hbuf, elrz, errz, b, xa, hstate,
                                       Wc, al + 128, ar + 128, hcb, elc, erc, zbuf, N);
    else
      kb_k<64><<<G32, 512, 0, stream>>>(rp, srcs, hbuf, elrz, errz, b, xa, hstate,
                                        Wc, al + 128, ar + 128, hcb, elc, erc, zbuf, N);

    if (i == 47) {
      kc_k<2, false><<<G32, 512, 0, stream>>>(
          rp, srcs, hcb, elc, erc, b + 128, zbuf, hstate, proj_W, proj_b, outp,
          nullptr, nullptr, nullptr, nullptr, nullptr, nullptr, nullptr, nullptr, N);
    } else {
      int i2 = i + 1;
      bool enc2 = i2 < 24;
      int j2 = enc2 ? i2 : i2 - 24;
      int t2 = j2 >> 1, l2 = j2 & 1;
      int type2 = (enc2 ? 0 : 2) + l2;
      const float* Wn = Ws[type2];
      const float* aln = als[type2];
      const float* arn = ars[type2];
      const float* xan = nullptr;
      if (l2 == 0) {
        if (enc2) xan = x + (size_t)t2 * N * 2;   // next encoder layer0
        else if (t2 == 0) xan = zero2;            // first decoder step
        // else: decoder pred chain -> local p0,p1
      }
      const float* hxn = l2 ? hs1 : hs0;          // next cell's (old) hidden state
      if (l2)
        kc_k<64, true><<<G32, 512, 0, stream>>>(
            rp, srcs, hcb, elc, erc, b + 128, zbuf, hstate, proj_W, proj_b, outp,
            Wn, aln, arn, xan, hxn, hbuf, elrz, errz, N);
      else
        kc_k<2, true><<<G32, 512, 0, stream>>>(
            rp, srcs, hcb, elc, erc, b + 128, zbuf, hstate, proj_W, proj_b, outp,
            Wn, aln, arn, xan, hxn, hbuf, elrz, errz, N);
    }
  }
  (void)out_size; (void)n_in;
}